// Round 2
// baseline (633.995 us; speedup 1.0000x reference)
//
#include <hip/hip_runtime.h>
#include <hip/hip_bf16.h>
#include <stdint.h>

#define N_ 4096
#define H_ 1024
#define V_ 16384

using bf16x8 = __attribute__((ext_vector_type(8))) short;
using f32x16 = __attribute__((ext_vector_type(16))) float;

__device__ inline ushort f2bf(float f) {
    union { float f; uint32_t u; } v; v.f = f;
    uint32_t u = v.u;
    uint32_t lsb = (u >> 16) & 1u;
    u += 0x7fffu + lsb;
    return (ushort)(u >> 16);
}

// 8 floats -> 8 bf16 per thread
__global__ void cast_f32_to_bf16(const float* __restrict__ in, ushort* __restrict__ out) {
    size_t i = ((size_t)blockIdx.x * blockDim.x + threadIdx.x) * 8;
    float4 a = *(const float4*)(in + i);
    float4 b = *(const float4*)(in + i + 4);
    union { ushort h[8]; uint4 u; } p;
    p.h[0] = f2bf(a.x); p.h[1] = f2bf(a.y); p.h[2] = f2bf(a.z); p.h[3] = f2bf(a.w);
    p.h[4] = f2bf(b.x); p.h[5] = f2bf(b.y); p.h[6] = f2bf(b.z); p.h[7] = f2bf(b.w);
    *(uint4*)(out + i) = p.u;
}

#define BM 128
#define BN 128
#define BK 32

// C[m,v] = sum_k A[m,k]*W[v,k]; fused: sum((C + bias[v] - target[m,v])^2) per block
// LDS layout: fragment-ordered chunks. Chunk (rb, kh) = 32 rows x 16 k, stored so
// lane l owns 16B at chunk_base + l*16 == row (l&31), k = kh*16 + (l>>5)*8.
// global_load_lds (wave-uniform base + lane*16) then makes the LDS chunk exactly
// the MFMA 32x32x16 A/B fragment -> ds_read_b128 at base+lane*16 is conflict-free.
__global__ __launch_bounds__(256, 2) void gemm_mse(
    const ushort* __restrict__ Abf,   // N x H (bf16 bits)
    const ushort* __restrict__ Wbf,   // V x H (bf16 bits)
    const float*  __restrict__ target,// N x V
    const float*  __restrict__ bias,  // V
    float* __restrict__ partials)     // one per block
{
    __shared__ ushort As[8 * 512];   // 4 rowblocks x 2 khalves, 1KB chunks
    __shared__ ushort Bs[8 * 512];
    __shared__ float red[4];

    const int tid  = threadIdx.x;
    const int w    = tid >> 6;        // wave 0..3
    const int lane = tid & 63;
    const int l32  = lane & 31;
    const int half = lane >> 5;       // 0/1
    const int wm   = w >> 1;          // 2x2 wave grid, 64x64 each
    const int wn   = w & 1;

    const int rowBase = blockIdx.y * BM;  // N dim
    const int colBase = blockIdx.x * BN;  // V dim

    f32x16 acc[2][2];
#pragma unroll
    for (int i = 0; i < 2; ++i)
#pragma unroll
        for (int j = 0; j < 2; ++j)
#pragma unroll
            for (int r = 0; r < 16; ++r) acc[i][j][r] = 0.f;

    // staging: chunkid = w*2+c in 0..7; rb = chunkid>>1, kh = chunkid&1
    // lane address: row rb*32 + l32, k = k0 + kh*16 + half*8  (16B contiguous)
    for (int k0 = 0; k0 < H_; k0 += BK) {
        __syncthreads();
#pragma unroll
        for (int c = 0; c < 2; ++c) {
            const int chunkid = w * 2 + c;            // wave-uniform
            const int rb = chunkid >> 1;
            const int kh = chunkid & 1;
            const ushort* ga = Abf + (size_t)(rowBase + rb * 32 + l32) * H_ + k0 + kh * 16 + half * 8;
            __builtin_amdgcn_global_load_lds(
                (const __attribute__((address_space(1))) void*)ga,
                (__attribute__((address_space(3))) void*)(As + chunkid * 512), 16, 0, 0);
            const ushort* gb = Wbf + (size_t)(colBase + rb * 32 + l32) * H_ + k0 + kh * 16 + half * 8;
            __builtin_amdgcn_global_load_lds(
                (const __attribute__((address_space(1))) void*)gb,
                (__attribute__((address_space(3))) void*)(Bs + chunkid * 512), 16, 0, 0);
        }
        __syncthreads();

#pragma unroll
        for (int s = 0; s < 2; ++s) {   // k-half within BK
            bf16x8 af[2], bq[2];
#pragma unroll
            for (int i = 0; i < 2; ++i)
                af[i] = *(const bf16x8*)(As + (((wm * 2 + i) << 1) + s) * 512 + lane * 8);
#pragma unroll
            for (int j = 0; j < 2; ++j)
                bq[j] = *(const bf16x8*)(Bs + (((wn * 2 + j) << 1) + s) * 512 + lane * 8);
#pragma unroll
            for (int i = 0; i < 2; ++i)
#pragma unroll
                for (int j = 0; j < 2; ++j)
                    acc[i][j] = __builtin_amdgcn_mfma_f32_32x32x16_bf16(af[i], bq[j], acc[i][j], 0, 0, 0);
        }
    }

    // epilogue: 32x32 C/D layout: col = l32, row = (r&3) + 8*(r>>2) + 4*half
    float sum = 0.f;
    float biasj[2];
#pragma unroll
    for (int j = 0; j < 2; ++j) biasj[j] = bias[colBase + wn * 64 + j * 32 + l32];

#pragma unroll
    for (int i = 0; i < 2; ++i) {
#pragma unroll
        for (int r = 0; r < 16; ++r) {
            const int row = (r & 3) + 8 * (r >> 2) + 4 * half;
            const int gm = rowBase + wm * 64 + i * 32 + row;
            const float* trow = target + (size_t)gm * V_ + colBase + wn * 64 + l32;
#pragma unroll
            for (int j = 0; j < 2; ++j) {
                float d = acc[i][j][r] + biasj[j] - trow[j * 32];
                sum += d * d;
            }
        }
    }

    // block reduction
#pragma unroll
    for (int off = 32; off; off >>= 1) sum += __shfl_down(sum, off, 64);
    if (lane == 0) red[w] = sum;
    __syncthreads();
    if (tid == 0)
        partials[blockIdx.y * gridDim.x + blockIdx.x] = red[0] + red[1] + red[2] + red[3];
}

__global__ void finalize_kernel(const float* __restrict__ partials, float* __restrict__ out, int n) {
    float s = 0.f;
    for (int i = threadIdx.x; i < n; i += 256) s += partials[i];
#pragma unroll
    for (int off = 32; off; off >>= 1) s += __shfl_down(s, off, 64);
    __shared__ float red[4];
    const int w = threadIdx.x >> 6, lane = threadIdx.x & 63;
    if (lane == 0) red[w] = s;
    __syncthreads();
    if (threadIdx.x == 0)
        out[0] = (red[0] + red[1] + red[2] + red[3]) * (1.0f / ((float)N_ * (float)V_));
}

extern "C" void kernel_launch(void* const* d_in, const int* in_sizes, int n_in,
                              void* d_out, int out_size, void* d_ws, size_t ws_size,
                              hipStream_t stream) {
    const float* input  = (const float*)d_in[0];  // N x H
    const float* weight = (const float*)d_in[1];  // V x H
    const float* target = (const float*)d_in[2];  // N x V
    const float* bias   = (const float*)d_in[3];  // V
    float* out = (float*)d_out;

    ushort* Abf = (ushort*)d_ws;                      // N*H bf16
    ushort* Wbf = Abf + (size_t)N_ * H_;              // V*H bf16
    float* partials = (float*)(Wbf + (size_t)V_ * H_);// (N/128)*(V/128) floats

    cast_f32_to_bf16<<<(N_ * H_) / (256 * 8), 256, 0, stream>>>(input, Abf);
    cast_f32_to_bf16<<<(V_ * H_) / (256 * 8), 256, 0, stream>>>(weight, Wbf);

    dim3 grid(V_ / BN, N_ / BM);  // 128 x 32 = 4096 blocks
    gemm_mse<<<grid, 256, 0, stream>>>(Abf, Wbf, target, bias, partials);

    finalize_kernel<<<1, 256, 0, stream>>>(partials, out, (V_ / BN) * (N_ / BM));
}

// Round 3
// 527.992 us; speedup vs baseline: 1.2008x; 1.2008x over previous
//
#include <hip/hip_runtime.h>
#include <hip/hip_bf16.h>
#include <stdint.h>

#define N_ 4096
#define H_ 1024
#define V_ 16384

using bf16x8 = __attribute__((ext_vector_type(8))) short;
using f32x16 = __attribute__((ext_vector_type(16))) float;

__device__ inline ushort f2bf(float f) {
    union { float f; uint32_t u; } v; v.f = f;
    uint32_t u = v.u;
    uint32_t lsb = (u >> 16) & 1u;
    u += 0x7fffu + lsb;
    return (ushort)(u >> 16);
}

// 8 floats -> 8 bf16 per thread
__global__ void cast_f32_to_bf16(const float* __restrict__ in, ushort* __restrict__ out) {
    size_t i = ((size_t)blockIdx.x * blockDim.x + threadIdx.x) * 8;
    float4 a = *(const float4*)(in + i);
    float4 b = *(const float4*)(in + i + 4);
    union { ushort h[8]; uint4 u; } p;
    p.h[0] = f2bf(a.x); p.h[1] = f2bf(a.y); p.h[2] = f2bf(a.z); p.h[3] = f2bf(a.w);
    p.h[4] = f2bf(b.x); p.h[5] = f2bf(b.y); p.h[6] = f2bf(b.z); p.h[7] = f2bf(b.w);
    *(uint4*)(out + i) = p.u;
}

#define BM 128
#define BN 128
#define BK 32

// C[m,v] = sum_k A[m,k]*W[v,k]; fused MSE partial per block.
//
// LDS: 8 chunks of 1KB per operand. Chunk ch covers rows ch*16..+15, k 0..31.
// Staging (one global_load_lds per chunk, 16 rows x 64B contiguous segments):
//   lane l -> row l>>2, k-quarter kq = (l&3) ^ f(l>>2),  f(r)=(r+(r>>2))&3
//   (slot l = lane l: LDS dst is wave-uniform base + lane*16)
// Read (32x32x16 fragment, lane l wants row l&31, kq = s*2 + (l>>5)):
//   slot = (row&15)*4 + (kq ^ f(row&15)), chunk += (row>>4)
//   -> every aligned 8-lane group hits 8 distinct bank groups: conflict-free.
__global__ __launch_bounds__(256, 2) void gemm_mse(
    const ushort* __restrict__ Abf,   // N x H (bf16 bits)
    const ushort* __restrict__ Wbf,   // V x H (bf16 bits)
    const float*  __restrict__ target,// N x V
    const float*  __restrict__ bias,  // V
    float* __restrict__ partials)     // one per block
{
    __shared__ ushort As[8 * 512];
    __shared__ ushort Bs[8 * 512];
    __shared__ float red[4];

    const int tid  = threadIdx.x;
    const int w    = tid >> 6;        // wave 0..3
    const int lane = tid & 63;
    const int l32  = lane & 31;
    const int half = lane >> 5;       // 0/1 (k-block for A/B frags)
    const int wm   = w >> 1;          // 2x2 wave grid, 64x64 each
    const int wn   = w & 1;

    const int rowBase = blockIdx.y * BM;  // N dim
    const int colBase = blockIdx.x * BN;  // V dim

    f32x16 acc[2][2];
#pragma unroll
    for (int i = 0; i < 2; ++i)
#pragma unroll
        for (int j = 0; j < 2; ++j)
#pragma unroll
            for (int r = 0; r < 16; ++r) acc[i][j][r] = 0.f;

    // ---- staging lane params (row-major 64B segments, swizzled k-quarter)
    const int ldrow = lane >> 2;                          // 0..15
    const int ldkq  = (lane & 3) ^ ((ldrow + (ldrow >> 2)) & 3);

    // ---- read pointers (lane-constant), conflict-free swizzled
    const int rl  = lane & 15;
    const int rcb = (lane >> 4) & 1;                      // which 16-row chunk
    const int fl  = (rl + (rl >> 2)) & 3;
    const ushort* aPtr[2][2];
    const ushort* bPtr[2][2];
#pragma unroll
    for (int i = 0; i < 2; ++i)
#pragma unroll
        for (int s = 0; s < 2; ++s) {
            const int slot = rl * 4 + ((s * 2 + half) ^ fl);
            aPtr[i][s] = As + (wm * 4 + i * 2 + rcb) * 512 + slot * 8;
            bPtr[i][s] = Bs + (wn * 4 + i * 2 + rcb) * 512 + slot * 8;
        }

    for (int k0 = 0; k0 < H_; k0 += BK) {
        __syncthreads();
#pragma unroll
        for (int c = 0; c < 2; ++c) {
            const int chunkid = w * 2 + c;                // wave-uniform 0..7
            const ushort* ga = Abf + (size_t)(rowBase + chunkid * 16 + ldrow) * H_ + k0 + ldkq * 8;
            __builtin_amdgcn_global_load_lds(
                (const __attribute__((address_space(1))) void*)ga,
                (__attribute__((address_space(3))) void*)(As + chunkid * 512), 16, 0, 0);
            const ushort* gb = Wbf + (size_t)(colBase + chunkid * 16 + ldrow) * H_ + k0 + ldkq * 8;
            __builtin_amdgcn_global_load_lds(
                (const __attribute__((address_space(1))) void*)gb,
                (__attribute__((address_space(3))) void*)(Bs + chunkid * 512), 16, 0, 0);
        }
        __syncthreads();

#pragma unroll
        for (int s = 0; s < 2; ++s) {   // k-half within BK
            bf16x8 af[2], bq[2];
#pragma unroll
            for (int i = 0; i < 2; ++i) af[i] = *(const bf16x8*)aPtr[i][s];
#pragma unroll
            for (int j = 0; j < 2; ++j) bq[j] = *(const bf16x8*)bPtr[j][s];
#pragma unroll
            for (int i = 0; i < 2; ++i)
#pragma unroll
                for (int j = 0; j < 2; ++j)
                    acc[i][j] = __builtin_amdgcn_mfma_f32_32x32x16_bf16(af[i], bq[j], acc[i][j], 0, 0, 0);
        }
    }

    // epilogue: 32x32 C/D layout: col = l32, row = (r&3) + 8*(r>>2) + 4*half
    float sum = 0.f;
    float biasj[2];
#pragma unroll
    for (int j = 0; j < 2; ++j) biasj[j] = bias[colBase + wn * 64 + j * 32 + l32];

#pragma unroll
    for (int i = 0; i < 2; ++i) {
#pragma unroll
        for (int r = 0; r < 16; ++r) {
            const int row = (r & 3) + 8 * (r >> 2) + 4 * half;
            const int gm = rowBase + wm * 64 + i * 32 + row;
            const float* trow = target + (size_t)gm * V_ + colBase + wn * 64 + l32;
#pragma unroll
            for (int j = 0; j < 2; ++j) {
                float d = acc[i][j][r] + biasj[j] - trow[j * 32];
                sum += d * d;
            }
        }
    }

    // block reduction
#pragma unroll
    for (int off = 32; off; off >>= 1) sum += __shfl_down(sum, off, 64);
    if (lane == 0) red[w] = sum;
    __syncthreads();
    if (tid == 0)
        partials[blockIdx.y * gridDim.x + blockIdx.x] = red[0] + red[1] + red[2] + red[3];
}

__global__ void finalize_kernel(const float* __restrict__ partials, float* __restrict__ out, int n) {
    float s = 0.f;
    for (int i = threadIdx.x; i < n; i += 256) s += partials[i];
#pragma unroll
    for (int off = 32; off; off >>= 1) s += __shfl_down(s, off, 64);
    __shared__ float red[4];
    const int w = threadIdx.x >> 6, lane = threadIdx.x & 63;
    if (lane == 0) red[w] = s;
    __syncthreads();
    if (threadIdx.x == 0)
        out[0] = (red[0] + red[1] + red[2] + red[3]) * (1.0f / ((float)N_ * (float)V_));
}

extern "C" void kernel_launch(void* const* d_in, const int* in_sizes, int n_in,
                              void* d_out, int out_size, void* d_ws, size_t ws_size,
                              hipStream_t stream) {
    const float* input  = (const float*)d_in[0];  // N x H
    const float* weight = (const float*)d_in[1];  // V x H
    const float* target = (const float*)d_in[2];  // N x V
    const float* bias   = (const float*)d_in[3];  // V
    float* out = (float*)d_out;

    ushort* Abf = (ushort*)d_ws;                      // N*H bf16
    ushort* Wbf = Abf + (size_t)N_ * H_;              // V*H bf16
    float* partials = (float*)(Wbf + (size_t)V_ * H_);// (N/128)*(V/128) floats

    cast_f32_to_bf16<<<(N_ * H_) / (256 * 8), 256, 0, stream>>>(input, Abf);
    cast_f32_to_bf16<<<(V_ * H_) / (256 * 8), 256, 0, stream>>>(weight, Wbf);

    dim3 grid(V_ / BN, N_ / BM);  // 128 x 32 = 4096 blocks
    gemm_mse<<<grid, 256, 0, stream>>>(Abf, Wbf, target, bias, partials);

    finalize_kernel<<<1, 256, 0, stream>>>(partials, out, (V_ / BN) * (N_ / BM));
}

// Round 4
// 457.878 us; speedup vs baseline: 1.3846x; 1.1531x over previous
//
#include <hip/hip_runtime.h>
#include <hip/hip_bf16.h>
#include <stdint.h>

#define N_ 4096
#define H_ 1024
#define V_ 16384

using i32x8  = __attribute__((ext_vector_type(8))) int;
using f32x16 = __attribute__((ext_vector_type(16))) float;

// 8 floats -> 8 fp8 e4m3 (OCP on gfx950) per thread, RNE+sat via HW cvt
__global__ void cast_f32_to_fp8(const float* __restrict__ in, uint8_t* __restrict__ out) {
    size_t i = ((size_t)blockIdx.x * blockDim.x + threadIdx.x) * 8;
    float4 a = *(const float4*)(in + i);
    float4 b = *(const float4*)(in + i + 4);
    int lo = __builtin_amdgcn_cvt_pk_fp8_f32(a.x, a.y, 0, 0);
    lo     = __builtin_amdgcn_cvt_pk_fp8_f32(a.z, a.w, lo, 1);
    int hi = __builtin_amdgcn_cvt_pk_fp8_f32(b.x, b.y, 0, 0);
    hi     = __builtin_amdgcn_cvt_pk_fp8_f32(b.z, b.w, hi, 1);
    *(int2*)(out + i) = make_int2(lo, hi);
}

#define BM 128
#define BN 128
#define BK 64   // fp8: 64 bytes of K per iter

// C[m,v] = sum_k A[m,k]*W[v,k]; fused MSE partial per block.
// MX MFMA 32x32x64 f8f6f4 (fmt=fp8 e4m3), unit scales 0x7F (2^0) -> plain fp8 GEMM
// at the scaled-MFMA rate (m148 path).
//
// LDS: 8 chunks x 1KB per operand per iter. Chunk ch = rows ch*16..+15, k 0..63 (bytes).
// Staging (1 global_load_lds per chunk): lane l -> row l>>2 (64B contiguous rows),
//   k-quarter kq = (l&3) ^ f(l>>2), f(r)=(r+(r>>2))&3; slot = lane (base + l*16).
// Fragment read (lane l wants row l&31, k bytes [half*32,+32) = kq {2*half, 2*half+1}):
//   slot = rl*4 + (kq ^ f(rl)), rl = l&15, chunk selected by (l>>4)&1.
//   Same swizzle as R3 -> measured 0 bank conflicts.
// Any within-instruction k-permutation is common to A and B (identical staging/read)
// and cancels in the dot product; C/D layout is shape-determined (== bf16 32x32).
__global__ __launch_bounds__(256, 2) void gemm_mse(
    const uint8_t* __restrict__ A8,   // N x H fp8
    const uint8_t* __restrict__ W8,   // V x H fp8
    const float*  __restrict__ target,// N x V
    const float*  __restrict__ bias,  // V
    float* __restrict__ partials)     // one per block
{
    __shared__ uint8_t As[8 * 1024];
    __shared__ uint8_t Bs[8 * 1024];
    __shared__ float red[4];

    const int tid  = threadIdx.x;
    const int w    = tid >> 6;        // wave 0..3
    const int lane = tid & 63;
    const int l32  = lane & 31;
    const int half = lane >> 5;       // 0/1: k-half of the 64-wide K per inst
    const int wm   = w >> 1;          // 2x2 wave grid, 64x64 each
    const int wn   = w & 1;

    const int rowBase = blockIdx.y * BM;  // N dim
    const int colBase = blockIdx.x * BN;  // V dim

    f32x16 acc[2][2];
#pragma unroll
    for (int i = 0; i < 2; ++i)
#pragma unroll
        for (int j = 0; j < 2; ++j)
#pragma unroll
            for (int r = 0; r < 16; ++r) acc[i][j][r] = 0.f;

    // ---- staging lane params: 16 rows x 64B per 1KB chunk, swizzled 16B k-quarter
    const int ldrow = lane >> 2;                          // 0..15
    const int ldkq  = (lane & 3) ^ ((ldrow + (ldrow >> 2)) & 3);

    // ---- fragment read pointers (lane-constant), conflict-free swizzled
    const int rl  = lane & 15;
    const int rcb = (lane >> 4) & 1;                      // which 16-row chunk
    const int fl  = (rl + (rl >> 2)) & 3;
    const uint8_t* aPtr[2][2];   // [i][c]: c = which 16B of the lane's 32 k-bytes
    const uint8_t* bPtr[2][2];
#pragma unroll
    for (int i = 0; i < 2; ++i)
#pragma unroll
        for (int c = 0; c < 2; ++c) {
            const int slot = rl * 4 + (((half << 1) + c) ^ fl);
            aPtr[i][c] = As + (size_t)((wm * 2 + i) * 2 + rcb) * 1024 + slot * 16;
            bPtr[i][c] = Bs + (size_t)((wn * 2 + i) * 2 + rcb) * 1024 + slot * 16;
        }

    for (int k0 = 0; k0 < H_; k0 += BK) {   // 16 iters
        __syncthreads();
#pragma unroll
        for (int c = 0; c < 2; ++c) {
            const int chunkid = w * 2 + c;                // wave-uniform 0..7
            const uint8_t* ga = A8 + (size_t)(rowBase + chunkid * 16 + ldrow) * H_ + k0 + ldkq * 16;
            __builtin_amdgcn_global_load_lds(
                (const __attribute__((address_space(1))) void*)ga,
                (__attribute__((address_space(3))) void*)(As + chunkid * 1024), 16, 0, 0);
            const uint8_t* gb = W8 + (size_t)(colBase + chunkid * 16 + ldrow) * H_ + k0 + ldkq * 16;
            __builtin_amdgcn_global_load_lds(
                (const __attribute__((address_space(1))) void*)gb,
                (__attribute__((address_space(3))) void*)(Bs + chunkid * 1024), 16, 0, 0);
        }
        __syncthreads();

        i32x8 af[2], bq[2];
#pragma unroll
        for (int i = 0; i < 2; ++i) {
            int4 a0 = *(const int4*)aPtr[i][0];
            int4 a1 = *(const int4*)aPtr[i][1];
            af[i][0] = a0.x; af[i][1] = a0.y; af[i][2] = a0.z; af[i][3] = a0.w;
            af[i][4] = a1.x; af[i][5] = a1.y; af[i][6] = a1.z; af[i][7] = a1.w;
            int4 b0 = *(const int4*)bPtr[i][0];
            int4 b1 = *(const int4*)bPtr[i][1];
            bq[i][0] = b0.x; bq[i][1] = b0.y; bq[i][2] = b0.z; bq[i][3] = b0.w;
            bq[i][4] = b1.x; bq[i][5] = b1.y; bq[i][6] = b1.z; bq[i][7] = b1.w;
        }
#pragma unroll
        for (int i = 0; i < 2; ++i)
#pragma unroll
            for (int j = 0; j < 2; ++j)
                acc[i][j] = __builtin_amdgcn_mfma_scale_f32_32x32x64_f8f6f4(
                    af[i], bq[j], acc[i][j],
                    0 /*cbsz: fp8 e4m3*/, 0 /*blgp: fp8 e4m3*/,
                    0, 0x7F7F7F7F,   // A scales: 2^0
                    0, 0x7F7F7F7F);  // B scales: 2^0
    }

    // epilogue: 32x32 C/D layout: col = l32, row = (r&3) + 8*(r>>2) + 4*half
    float sum = 0.f;
    float biasj[2];
#pragma unroll
    for (int j = 0; j < 2; ++j) biasj[j] = bias[colBase + wn * 64 + j * 32 + l32];

#pragma unroll
    for (int i = 0; i < 2; ++i) {
#pragma unroll
        for (int r = 0; r < 16; ++r) {
            const int row = (r & 3) + 8 * (r >> 2) + 4 * half;
            const int gm = rowBase + wm * 64 + i * 32 + row;
            const float* trow = target + (size_t)gm * V_ + colBase + wn * 64 + l32;
#pragma unroll
            for (int j = 0; j < 2; ++j) {
                float d = acc[i][j][r] + biasj[j] - trow[j * 32];
                sum += d * d;
            }
        }
    }

    // block reduction
#pragma unroll
    for (int off = 32; off; off >>= 1) sum += __shfl_down(sum, off, 64);
    if (lane == 0) red[w] = sum;
    __syncthreads();
    if (tid == 0)
        partials[blockIdx.y * gridDim.x + blockIdx.x] = red[0] + red[1] + red[2] + red[3];
}

__global__ void finalize_kernel(const float* __restrict__ partials, float* __restrict__ out, int n) {
    float s = 0.f;
    for (int i = threadIdx.x; i < n; i += 256) s += partials[i];
#pragma unroll
    for (int off = 32; off; off >>= 1) s += __shfl_down(s, off, 64);
    __shared__ float red[4];
    const int w = threadIdx.x >> 6, lane = threadIdx.x & 63;
    if (lane == 0) red[w] = s;
    __syncthreads();
    if (threadIdx.x == 0)
        out[0] = (red[0] + red[1] + red[2] + red[3]) * (1.0f / ((float)N_ * (float)V_));
}

extern "C" void kernel_launch(void* const* d_in, const int* in_sizes, int n_in,
                              void* d_out, int out_size, void* d_ws, size_t ws_size,
                              hipStream_t stream) {
    const float* input  = (const float*)d_in[0];  // N x H
    const float* weight = (const float*)d_in[1];  // V x H
    const float* target = (const float*)d_in[2];  // N x V
    const float* bias   = (const float*)d_in[3];  // V
    float* out = (float*)d_out;

    uint8_t* A8 = (uint8_t*)d_ws;                       // N*H fp8
    uint8_t* W8 = A8 + (size_t)N_ * H_;                 // V*H fp8
    float* partials = (float*)(W8 + (size_t)V_ * H_);   // (N/128)*(V/128) floats

    cast_f32_to_fp8<<<(N_ * H_) / (256 * 8), 256, 0, stream>>>(input, A8);
    cast_f32_to_fp8<<<(V_ * H_) / (256 * 8), 256, 0, stream>>>(weight, W8);

    dim3 grid(V_ / BN, N_ / BM);  // 128 x 32 = 4096 blocks
    gemm_mse<<<grid, 256, 0, stream>>>(A8, W8, target, bias, partials);

    finalize_kernel<<<1, 256, 0, stream>>>(partials, out, (V_ / BN) * (N_ / BM));
}

// Round 5
// 451.164 us; speedup vs baseline: 1.4052x; 1.0149x over previous
//
#include <hip/hip_runtime.h>
#include <hip/hip_bf16.h>
#include <stdint.h>

#define N_ 4096
#define H_ 1024
#define V_ 16384

using i32x8  = __attribute__((ext_vector_type(8))) int;
using f32x16 = __attribute__((ext_vector_type(16))) float;

// 8 floats -> 8 fp8 e4m3 (OCP) per thread; both tensors in one launch
__global__ void cast2_f32_to_fp8(const float* __restrict__ in0, uint8_t* __restrict__ out0,
                                 const float* __restrict__ in1, uint8_t* __restrict__ out1,
                                 int nblk0) {
    const float* in;
    uint8_t* out;
    int bid;
    if (blockIdx.x < (unsigned)nblk0) { in = in0; out = out0; bid = blockIdx.x; }
    else                              { in = in1; out = out1; bid = blockIdx.x - nblk0; }
    size_t i = ((size_t)bid * blockDim.x + threadIdx.x) * 8;
    float4 a = *(const float4*)(in + i);
    float4 b = *(const float4*)(in + i + 4);
    int lo = __builtin_amdgcn_cvt_pk_fp8_f32(a.x, a.y, 0, 0);
    lo     = __builtin_amdgcn_cvt_pk_fp8_f32(a.z, a.w, lo, 1);
    int hi = __builtin_amdgcn_cvt_pk_fp8_f32(b.x, b.y, 0, 0);
    hi     = __builtin_amdgcn_cvt_pk_fp8_f32(b.z, b.w, hi, 1);
    *(int2*)(out + i) = make_int2(lo, hi);
}

#define BM 128
#define BN 128
#define BK 128   // two K=64 sub-steps per barrier pair (halves barrier drains)

// C[m,v] = sum_k A[m,k]*W[v,k]; fused MSE partial per block.
// Core: MX MFMA 32x32x64 f8f6f4 (fp8 e4m3, unit scales 0x7F) — R4's verified path.
// LDS per operand: 2 sub-tiles (K-halves) x 8 chunks x 1KB. Staging/read swizzle
// identical to R4 (measured 0 bank conflicts): chunk = 16 rows x 64B rows,
// lane l stages row l>>2, k-quarter (l&3)^f(l>>2), f(r)=(r+(r>>2))&3;
// fragment read slot = rl*4 + (kq ^ f(rl)).
// Block->tile mapping is XCD-aware: xcd = flat&7 owns a 16x32 band of tiles.
__global__ __launch_bounds__(256, 2) void gemm_mse(
    const uint8_t* __restrict__ A8,   // N x H fp8
    const uint8_t* __restrict__ W8,   // V x H fp8
    const float*  __restrict__ target,// N x V
    const float*  __restrict__ bias,  // V
    float* __restrict__ partials)     // one per block
{
    __shared__ uint8_t As[2 * 8 * 1024];
    __shared__ uint8_t Bs[2 * 8 * 1024];
    __shared__ float red[4];

    const int tid  = threadIdx.x;
    const int w    = tid >> 6;        // wave 0..3
    const int lane = tid & 63;
    const int l32  = lane & 31;
    const int half = lane >> 5;       // 0/1: k-half within one instruction's K=64
    const int wm   = w >> 1;          // 2x2 wave grid, 64x64 each
    const int wn   = w & 1;

    // XCD-aware tile mapping: 128 col-tiles x 32 row-tiles
    const int flat = blockIdx.x;
    const int xcd  = flat & 7;
    const int idx  = flat >> 3;                 // 0..511 per XCD
    const int tx   = xcd * 16 + (idx & 15);     // V tile 0..127
    const int ty   = idx >> 4;                  // N tile 0..31

    const int rowBase = ty * BM;  // N dim
    const int colBase = tx * BN;  // V dim

    f32x16 acc[2][2];
#pragma unroll
    for (int i = 0; i < 2; ++i)
#pragma unroll
        for (int j = 0; j < 2; ++j)
#pragma unroll
            for (int r = 0; r < 16; ++r) acc[i][j][r] = 0.f;

    // ---- staging lane params: 16 rows x 64B per 1KB chunk, swizzled 16B k-quarter
    const int ldrow = lane >> 2;                          // 0..15
    const int ldkq  = (lane & 3) ^ ((ldrow + (ldrow >> 2)) & 3);

    // ---- fragment read pointers (lane-constant), conflict-free swizzled
    const int rl  = lane & 15;
    const int rcb = (lane >> 4) & 1;                      // which 16-row chunk
    const int fl  = (rl + (rl >> 2)) & 3;
    const uint8_t* aPtr[2][2];   // [i][c]: c = which 16B of the lane's 32 k-bytes
    const uint8_t* bPtr[2][2];
#pragma unroll
    for (int i = 0; i < 2; ++i)
#pragma unroll
        for (int c = 0; c < 2; ++c) {
            const int slot = rl * 4 + (((half << 1) + c) ^ fl);
            aPtr[i][c] = As + (size_t)((wm * 2 + i) * 2 + rcb) * 1024 + slot * 16;
            bPtr[i][c] = Bs + (size_t)((wn * 2 + i) * 2 + rcb) * 1024 + slot * 16;
        }

    for (int k0 = 0; k0 < H_; k0 += BK) {   // 8 iters
        __syncthreads();
#pragma unroll
        for (int h = 0; h < 2; ++h) {       // K-64 half of the BK=128 tile
#pragma unroll
            for (int c = 0; c < 2; ++c) {
                const int chunkid = w * 2 + c;            // wave-uniform 0..7
                const int kOff = k0 + h * 64 + ldkq * 16;
                const uint8_t* ga = A8 + (size_t)(rowBase + chunkid * 16 + ldrow) * H_ + kOff;
                __builtin_amdgcn_global_load_lds(
                    (const __attribute__((address_space(1))) void*)ga,
                    (__attribute__((address_space(3))) void*)(As + h * 8192 + chunkid * 1024), 16, 0, 0);
                const uint8_t* gb = W8 + (size_t)(colBase + chunkid * 16 + ldrow) * H_ + kOff;
                __builtin_amdgcn_global_load_lds(
                    (const __attribute__((address_space(1))) void*)gb,
                    (__attribute__((address_space(3))) void*)(Bs + h * 8192 + chunkid * 1024), 16, 0, 0);
            }
        }
        __syncthreads();

#pragma unroll
        for (int h = 0; h < 2; ++h) {
            i32x8 af[2], bq[2];
#pragma unroll
            for (int i = 0; i < 2; ++i) {
                int4 a0 = *(const int4*)(aPtr[i][0] + h * 8192);
                int4 a1 = *(const int4*)(aPtr[i][1] + h * 8192);
                af[i][0] = a0.x; af[i][1] = a0.y; af[i][2] = a0.z; af[i][3] = a0.w;
                af[i][4] = a1.x; af[i][5] = a1.y; af[i][6] = a1.z; af[i][7] = a1.w;
                int4 b0 = *(const int4*)(bPtr[i][0] + h * 8192);
                int4 b1 = *(const int4*)(bPtr[i][1] + h * 8192);
                bq[i][0] = b0.x; bq[i][1] = b0.y; bq[i][2] = b0.z; bq[i][3] = b0.w;
                bq[i][4] = b1.x; bq[i][5] = b1.y; bq[i][6] = b1.z; bq[i][7] = b1.w;
            }
#pragma unroll
            for (int i = 0; i < 2; ++i)
#pragma unroll
                for (int j = 0; j < 2; ++j)
                    acc[i][j] = __builtin_amdgcn_mfma_scale_f32_32x32x64_f8f6f4(
                        af[i], bq[j], acc[i][j],
                        0 /*cbsz: fp8 e4m3*/, 0 /*blgp: fp8 e4m3*/,
                        0, 0x7F7F7F7F,   // A scales: 2^0
                        0, 0x7F7F7F7F);  // B scales: 2^0
        }
    }

    // epilogue: 32x32 C/D layout: col = l32, row = (r&3) + 8*(r>>2) + 4*half
    float sum = 0.f;
    float biasj[2];
#pragma unroll
    for (int j = 0; j < 2; ++j) biasj[j] = bias[colBase + wn * 64 + j * 32 + l32];

#pragma unroll
    for (int i = 0; i < 2; ++i) {
#pragma unroll
        for (int r = 0; r < 16; ++r) {
            const int row = (r & 3) + 8 * (r >> 2) + 4 * half;
            const int gm = rowBase + wm * 64 + i * 32 + row;
            const float* trow = target + (size_t)gm * V_ + colBase + wn * 64 + l32;
#pragma unroll
            for (int j = 0; j < 2; ++j) {
                float d = acc[i][j][r] + biasj[j] - trow[j * 32];
                sum += d * d;
            }
        }
    }

    // block reduction
#pragma unroll
    for (int off = 32; off; off >>= 1) sum += __shfl_down(sum, off, 64);
    if (lane == 0) red[w] = sum;
    __syncthreads();
    if (tid == 0)
        partials[flat] = red[0] + red[1] + red[2] + red[3];
}

__global__ void finalize_kernel(const float* __restrict__ partials, float* __restrict__ out, int n) {
    float s = 0.f;
    for (int i = threadIdx.x; i < n; i += 256) s += partials[i];
#pragma unroll
    for (int off = 32; off; off >>= 1) s += __shfl_down(s, off, 64);
    __shared__ float red[4];
    const int w = threadIdx.x >> 6, lane = threadIdx.x & 63;
    if (lane == 0) red[w] = s;
    __syncthreads();
    if (threadIdx.x == 0)
        out[0] = (red[0] + red[1] + red[2] + red[3]) * (1.0f / ((float)N_ * (float)V_));
}

extern "C" void kernel_launch(void* const* d_in, const int* in_sizes, int n_in,
                              void* d_out, int out_size, void* d_ws, size_t ws_size,
                              hipStream_t stream) {
    const float* input  = (const float*)d_in[0];  // N x H
    const float* weight = (const float*)d_in[1];  // V x H
    const float* target = (const float*)d_in[2];  // N x V
    const float* bias   = (const float*)d_in[3];  // V
    float* out = (float*)d_out;

    uint8_t* A8 = (uint8_t*)d_ws;                       // N*H fp8
    uint8_t* W8 = A8 + (size_t)N_ * H_;                 // V*H fp8
    float* partials = (float*)(W8 + (size_t)V_ * H_);   // 4096 floats

    const int nblk0 = (N_ * H_) / (256 * 8);            // 2048
    const int nblk1 = (V_ * H_) / (256 * 8);            // 8192
    cast2_f32_to_fp8<<<nblk0 + nblk1, 256, 0, stream>>>(input, A8, weight, W8, nblk0);

    const int nblocks = (V_ / BN) * (N_ / BM);          // 4096
    gemm_mse<<<nblocks, 256, 0, stream>>>(A8, W8, target, bias, partials);

    finalize_kernel<<<1, 256, 0, stream>>>(partials, out, nblocks);
}